// Round 5
// baseline (158.144 us; speedup 1.0000x reference)
//
#include <hip/hip_runtime.h>
#include <hip/hip_bf16.h>

// TriplesDistances: B=16, N=512, A=1024
// positions: float32 [B,N,3]; neighbors_j/k: int32 [B,N,A]; out: float32,
// (r_ij | r_ik | r_jk) each [B,N,A] concatenated flat.
//
// R10 post-mortem: fast_sqrt + 32 waves/CU = -0.7us. All fine-grain levers
// (MLP, TLP, LDS layout, VALU tail) measured, each <=1us. Remaining gap
// (~40us kernel vs ~29us mixed-stream floor) attributed to per-block ramp:
// at grid 8192 every block pays stage+barrier (~700-1000cyc) before any
// gather, 32x sequentially per CU, and re-stages the same batch table.
// R11: grid 2048, 4 rows/block -> stage+barrier once per 4 rows; software
// pipeline: row r+1's index loads issue before row r's gather/compute/store
// so index latency hides under compute. Register budget ~58 VGPR fits
// (256,8) = 32 waves/CU.

namespace {
constexpr int kB = 16;
constexpr int kN = 512;
constexpr int kA = 1024;
constexpr long long kBNA = (long long)kB * kN * kA;  // 8,388,608

typedef int   iv4 __attribute__((ext_vector_type(4)));
typedef float fv4 __attribute__((ext_vector_type(4)));

__device__ __forceinline__ float fast_sqrt(float s) {
    // absmax tolerance 1.5e-2 >> 1-2 ULP of raw v_sqrt_f32; sqrt(0)=0
    // preserves safe_norm semantics.
    float r;
    asm("v_sqrt_f32 %0, %1" : "=v"(r) : "v"(s));
    return r;
}
}  // namespace

__global__ __launch_bounds__(256, 8) void TriplesDistances_kernel(
    const float* __restrict__ pos,   // f32 [B*N*3]
    const int* __restrict__ nj,      // int32 [B*N*A]
    const int* __restrict__ nk,      // int32 [B*N*A]
    float* __restrict__ out)         // f32 [3*B*N*A]
{
    __shared__ fv4 spos[kN];  // 8 KB, float4-padded positions of this batch

    const int bid = blockIdx.x;        // 0..2047
    const int b   = bid >> 7;          // batch (128 blocks per batch)
    const int n0  = (bid & 127) << 2;  // first of 4 rows
    const int tid = threadIdx.x;
    const int wave = tid >> 6;         // quarter-row per wave
    const int lane = tid & 63;

    // Per-wave base offset for row n0; consecutive rows are +kA.
    const long long base0 =
        ((long long)b * kN + n0) * kA + wave * 256 + lane * 4;

    // ---- Prefetch row 0 indices BEFORE staging (in flight across it). ----
    iv4 j4 = *(const iv4*)(nj + base0);
    iv4 k4 = *(const iv4*)(nk + base0);

    // Stage batch-b positions: 1536 packed floats -> padded float4 layout.
    {
        const float* p = pos + (size_t)b * (kN * 3);
#pragma unroll
        for (int t = 0; t < 6; ++t) {
            const int e = tid + t * 256;
            const int a = e / 3;         // magic-mul, no HW div
            const int c = e - a * 3;
            ((float*)&spos[a])[c] = p[e];
        }
    }
    __syncthreads();                    // spos ready

    // ---- 4 rows, software-pipelined: next row's indices load during ----
    // ---- current row's gather/compute/store.                         ----
#pragma unroll
    for (int r = 0; r < 4; ++r) {
        const long long off = base0 + (long long)r * kA;

        // Prefetch next row's indices first (dead in last iteration).
        iv4 j4n, k4n;
        if (r < 3) {
            j4n = *(const iv4*)(nj + off + kA);
            k4n = *(const iv4*)(nk + off + kA);
        }

        const fv4 pi = spos[n0 + r];     // wave-uniform -> broadcast read
        const float xi = pi.x, yi = pi.y, zi = pi.z;

        const int js[4] = {j4.x, j4.y, j4.z, j4.w};
        const int ks[4] = {k4.x, k4.y, k4.z, k4.w};

        fv4 vij, vik, vjk;
        float* rij = (float*)&vij;
        float* rik = (float*)&vik;
        float* rjk = (float*)&vjk;

        // Gather + compute in pairs of points: 4x ds_read_b128 window
        // (16 regs) keeps peak VGPR under the (256,8) 64-reg cap.
#pragma unroll
        for (int p = 0; p < 2; ++p) {
            const fv4 pj0 = spos[js[2 * p + 0]];
            const fv4 pk0 = spos[ks[2 * p + 0]];
            const fv4 pj1 = spos[js[2 * p + 1]];
            const fv4 pk1 = spos[ks[2 * p + 1]];

            float dx = pj0.x - xi, dy = pj0.y - yi, dz = pj0.z - zi;
            rij[2 * p + 0] = fast_sqrt(dx * dx + dy * dy + dz * dz);
            dx = pk0.x - xi; dy = pk0.y - yi; dz = pk0.z - zi;
            rik[2 * p + 0] = fast_sqrt(dx * dx + dy * dy + dz * dz);
            dx = pj0.x - pk0.x; dy = pj0.y - pk0.y; dz = pj0.z - pk0.z;
            rjk[2 * p + 0] = fast_sqrt(dx * dx + dy * dy + dz * dz);

            dx = pj1.x - xi; dy = pj1.y - yi; dz = pj1.z - zi;
            rij[2 * p + 1] = fast_sqrt(dx * dx + dy * dy + dz * dz);
            dx = pk1.x - xi; dy = pk1.y - yi; dz = pk1.z - zi;
            rik[2 * p + 1] = fast_sqrt(dx * dx + dy * dy + dz * dz);
            dx = pj1.x - pk1.x; dy = pj1.y - pk1.y; dz = pj1.z - pk1.z;
            rjk[2 * p + 1] = fast_sqrt(dx * dx + dy * dy + dz * dz);
        }

        // 1 KB coalesced plain stores (overwrite poison-dirty L2 lines).
        *(fv4*)(out + off)            = vij;
        *(fv4*)(out + kBNA + off)     = vik;
        *(fv4*)(out + 2 * kBNA + off) = vjk;

        j4 = j4n;  // rotate pipeline (dead after last iteration)
        k4 = k4n;
    }
}

extern "C" void kernel_launch(void* const* d_in, const int* in_sizes, int n_in,
                              void* d_out, int out_size, void* d_ws, size_t ws_size,
                              hipStream_t stream) {
    const float* pos = (const float*)d_in[0];
    const int* nj = (const int*)d_in[1];
    const int* nk = (const int*)d_in[2];
    float* out = (float*)d_out;

    // 4 rows per block (quarter-row per wave per iter): grid = B*N/4 = 2048.
    TriplesDistances_kernel<<<kB * (kN / 4), 256, 0, stream>>>(pos, nj, nk, out);
}

// Round 6
// 153.856 us; speedup vs baseline: 1.0279x; 1.0279x over previous
//
#include <hip/hip_runtime.h>
#include <hip/hip_bf16.h>

// TriplesDistances: B=16, N=512, A=1024
// positions: float32 [B,N,3]; neighbors_j/k: int32 [B,N,A]; out: float32,
// (r_ij | r_ik | r_jk) each [B,N,A] concatenated flat.
//
// R11 post-mortem: intra-wave 4-row pipeline REGRESSED (+4.3us). Lesson:
// R10's many-tiny-independent-blocks structure self-pipelines (32 resident
// waves/CU at staggered phases); explicit serial rounds inside a wave are
// strictly worse. Reverted to R10 structure (best: 153.9).
// Component model: kernel ~36us vs 25.6us per-CU HBM floor (640KB/CU at
// 25GB/s/CU) -> ~71% mixed-stream efficiency vs fills' 86%.
// R12 (last lever): nontemporal hints on the zero-reuse streams. idx reads
// (each line read once) and output stores (each line written once) get nt
// -> no L2 allocate/evict round-trip; only the reused 6KB position table
// stays on the caching path. Pre-commit: +/-1us => declare roofline.

namespace {
constexpr int kB = 16;
constexpr int kN = 512;
constexpr int kA = 1024;
constexpr long long kBNA = (long long)kB * kN * kA;  // 8,388,608

typedef int   iv4 __attribute__((ext_vector_type(4)));
typedef float fv4 __attribute__((ext_vector_type(4)));

__device__ __forceinline__ float fast_sqrt(float s) {
    // absmax tolerance 1.5e-2 >> 1-2 ULP of raw v_sqrt_f32; sqrt(0)=0
    // preserves safe_norm semantics.
    float r;
    asm("v_sqrt_f32 %0, %1" : "=v"(r) : "v"(s));
    return r;
}
}  // namespace

__global__ __launch_bounds__(256, 8) void TriplesDistances_kernel(
    const float* __restrict__ pos,   // f32 [B*N*3]
    const int* __restrict__ nj,      // int32 [B*N*A]
    const int* __restrict__ nk,      // int32 [B*N*A]
    float* __restrict__ out)         // f32 [3*B*N*A]
{
    __shared__ fv4 spos[kN];  // 8 KB, float4-padded positions of this batch

    const int bid = blockIdx.x;        // 0..8191
    const int b   = bid >> 9;          // batch (512 blocks per batch)
    const int row = bid & 511;         // one row per block
    const int tid = threadIdx.x;

    const int wave = tid >> 6;          // quarter-row per wave
    const int lane = tid & 63;

    // 4 elems/thread; every iv4 load / fv4 store is 1 KB coalesced.
    const long long off = ((long long)b * kN + row) * kA + wave * 256 + lane * 4;

    // Issue both index loads first; in flight across staging.
    // Nontemporal: each index line is read exactly once -> no L2 allocate.
    const iv4 j4 = __builtin_nontemporal_load((const iv4*)(nj + off));
    const iv4 k4 = __builtin_nontemporal_load((const iv4*)(nk + off));

    // Stage batch-b positions: 1536 packed floats -> padded float4 layout.
    // (Cached path: 512 blocks share each batch's 6KB -> keep in L2/L3.)
    {
        const float* p = pos + (size_t)b * (kN * 3);
#pragma unroll
        for (int t = 0; t < 6; ++t) {
            const int e = tid + t * 256;
            const int a = e / 3;         // magic-mul, no HW div
            const int c = e - a * 3;
            ((float*)&spos[a])[c] = p[e];
        }
    }
    __syncthreads();                    // spos ready
    const fv4 pi = spos[row];
    const float xi = pi.x, yi = pi.y, zi = pi.z;

    const int js[4] = {j4.x, j4.y, j4.z, j4.w};
    const int ks[4] = {k4.x, k4.y, k4.z, k4.w};

    fv4 vij, vik, vjk;
    float* rij = (float*)&vij;
    float* rik = (float*)&vik;
    float* rjk = (float*)&vjk;

    // Gather + compute in pairs of points: 4x ds_read_b128 window (16 regs)
    // keeps peak VGPR under the (256,8) 64-reg cap.
#pragma unroll
    for (int p = 0; p < 2; ++p) {
        const fv4 pj0 = spos[js[2 * p + 0]];
        const fv4 pk0 = spos[ks[2 * p + 0]];
        const fv4 pj1 = spos[js[2 * p + 1]];
        const fv4 pk1 = spos[ks[2 * p + 1]];

        float dx = pj0.x - xi, dy = pj0.y - yi, dz = pj0.z - zi;
        rij[2 * p + 0] = fast_sqrt(dx * dx + dy * dy + dz * dz);
        dx = pk0.x - xi; dy = pk0.y - yi; dz = pk0.z - zi;
        rik[2 * p + 0] = fast_sqrt(dx * dx + dy * dy + dz * dz);
        dx = pj0.x - pk0.x; dy = pj0.y - pk0.y; dz = pj0.z - pk0.z;
        rjk[2 * p + 0] = fast_sqrt(dx * dx + dy * dy + dz * dz);

        dx = pj1.x - xi; dy = pj1.y - yi; dz = pj1.z - zi;
        rij[2 * p + 1] = fast_sqrt(dx * dx + dy * dy + dz * dz);
        dx = pk1.x - xi; dy = pk1.y - yi; dz = pk1.z - zi;
        rik[2 * p + 1] = fast_sqrt(dx * dx + dy * dy + dz * dz);
        dx = pj1.x - pk1.x; dy = pj1.y - pk1.y; dz = pj1.z - pk1.z;
        rjk[2 * p + 1] = fast_sqrt(dx * dx + dy * dy + dz * dz);
    }

    // Nontemporal 1 KB coalesced stores: each output line written exactly
    // once -> skip L2 allocate/evict round-trip, write-combine to HBM.
    __builtin_nontemporal_store(vij, (fv4*)(out + off));
    __builtin_nontemporal_store(vik, (fv4*)(out + kBNA + off));
    __builtin_nontemporal_store(vjk, (fv4*)(out + 2 * kBNA + off));
}

extern "C" void kernel_launch(void* const* d_in, const int* in_sizes, int n_in,
                              void* d_out, int out_size, void* d_ws, size_t ws_size,
                              hipStream_t stream) {
    const float* pos = (const float*)d_in[0];
    const int* nj = (const int*)d_in[1];
    const int* nk = (const int*)d_in[2];
    float* out = (float*)d_out;

    // 1 row per block (quarter-row per wave): grid = B * N = 8192 blocks.
    TriplesDistances_kernel<<<kB * kN, 256, 0, stream>>>(pos, nj, nk, out);
}